// Round 7
// baseline (322.557 us; speedup 1.0000x reference)
//
#include <hip/hip_runtime.h>
#include <math.h>

#define TT 512
#define CC 768
#define NH 12
#define HD 64
#define ADJF 12

typedef __attribute__((ext_vector_type(8))) short bf16x8;
typedef __attribute__((ext_vector_type(4))) short bf16x4;
typedef __attribute__((ext_vector_type(4))) float f32x4;
typedef __attribute__((ext_vector_type(2))) float f32x2v;
typedef __attribute__((ext_vector_type(2))) __bf16 bf16x2v;

__device__ __forceinline__ ushort f2bf(float x) {
    union { __bf16 b; ushort u; } c; c.b = (__bf16)x; return c.u;
}
__device__ __forceinline__ unsigned f2bf2(float lo, float hi) {
    f32x2v s; s[0] = lo; s[1] = hi;
    union { bf16x2v b; unsigned u; } c;
    c.b = __builtin_convertvector(s, bf16x2v);
    return c.u;
}

#define MFMA16(a, b, c) __builtin_amdgcn_mfma_f32_16x16x32_bf16((a), (b), (c), 0, 0, 0)

__device__ __forceinline__ f32x4 MFMA16K(bf16x4 a, bf16x4 b, f32x4 c) {
#if __has_builtin(__builtin_amdgcn_mfma_f32_16x16x16bf16_1k)
    return __builtin_amdgcn_mfma_f32_16x16x16bf16_1k(a, b, c, 0, 0, 0);
#else
    f32x4 d;
    asm("v_mfma_f32_16x16x16_bf16 %0, %1, %2, %3"
        : "=v"(d) : "v"(a), "v"(b), "v"(c));
    return d;
#endif
}

__device__ __forceinline__ float gelu_s(float x) {
    float x2 = x * x;
    float u  = __builtin_fmaf(x2, 0.025f, -0.166666666666667f);
    u        = __builtin_fmaf(x2, u, 1.0f);
    float er = 0.79788456080286536f * x * u;
    return 0.5f * x * (1.0f + er);
}

// ---------------------------------------------------------------------------
// adj body (identical math to R6's adj_f_mfma), parameterized by (q, b).
// ---------------------------------------------------------------------------
__device__ __forceinline__ void adj_body(
    const float* __restrict__ adj, const float* __restrict__ A1,
    const float* __restrict__ A2, const float* __restrict__ adjw_p,
    ushort* __restrict__ Fb, float* A1s, float* A2s, int q, int b)
{
    const int t = threadIdx.x;
    for (int i = t; i < 288; i += 256) { A1s[i] = A1[i]; A2s[i] = A2[i]; }
    __syncthreads();

    const int w = t >> 6, lane = t & 63, lx = lane & 15, qd = lane >> 4;
    const float adjw = adjw_p[0];

    union { bf16x8 v; ushort u[8]; } b1a, b1b;
#pragma unroll
    for (int j = 0; j < 8; j++) {
        int f = qd * 8 + j;
        b1a.u[j] = (f < 12) ? f2bf(A1s[lx * 12 + f]) : (ushort)0;
        b1b.u[j] = (lx < 8 && f < 12) ? f2bf(A1s[(16 + lx) * 12 + f]) : (ushort)0;
    }
    union { bf16x4 v; ushort u[4]; } B2lo, B2hi;
#pragma unroll
    for (int j = 0; j < 4; j++) {
        int elo = qd * 4 + j;
        int ehi = 16 + qd * 4 + j;
        B2lo.u[j] = (lx < 12) ? f2bf(adjw * A2s[lx * 24 + elo]) : (ushort)0;
        B2hi.u[j] = (lx < 12 && ehi < 24) ? f2bf(adjw * A2s[lx * 24 + ehi]) : (ushort)0;
    }

    const size_t prow = ((size_t)b * TT + q) * TT;
    ushort* outq = Fb + ((size_t)(b * NH) * TT + q) * TT;

    const float* arow = adj + (prow + w * 16 + lx) * ADJF;

    float4 c0 = (float4){0.f, 0.f, 0.f, 0.f}, c1 = c0;
    if (qd == 0)      { c0 = *(const float4*)(arow); c1 = *(const float4*)(arow + 4); }
    else if (qd == 1) { c0 = *(const float4*)(arow + 8); }

    for (int it = 0; it < 8; it++) {
        const int k0 = it * 64 + w * 16;

        const float* nrow = arow + 64 * ADJF;
        float4 n0 = c0, n1 = c1;
        if (it < 7) {
            if (qd == 0)      { n0 = *(const float4*)(nrow); n1 = *(const float4*)(nrow + 4); }
            else if (qd == 1) { n0 = *(const float4*)(nrow + 8); }
        }
        arow = nrow;

        union { bf16x8 v; unsigned u[4]; } afr;
        afr.u[0] = f2bf2(c0.x, c0.y);
        afr.u[1] = f2bf2(c0.z, c0.w);
        if (qd == 0) { afr.u[2] = f2bf2(c1.x, c1.y); afr.u[3] = f2bf2(c1.z, c1.w); }
        else         { afr.u[2] = 0;                 afr.u[3] = 0; }

        f32x4 zz = (f32x4){0.f, 0.f, 0.f, 0.f};
        f32x4 c1a = MFMA16(b1a.v, afr.v, zz);
        f32x4 c1b = MFMA16(b1b.v, afr.v, zz);

        union { bf16x4 v; unsigned u[2]; } ga, gb;
        ga.u[0] = f2bf2(gelu_s(c1a[0]), gelu_s(c1a[1]));
        ga.u[1] = f2bf2(gelu_s(c1a[2]), gelu_s(c1a[3]));
        gb.u[0] = f2bf2(gelu_s(c1b[0]), gelu_s(c1b[1]));
        gb.u[1] = f2bf2(gelu_s(c1b[2]), gelu_s(c1b[3]));

        f32x4 c2 = MFMA16K(ga.v, B2lo.v, MFMA16K(gb.v, B2hi.v, zz));

        if (lx < 12) {
            uint2 pk;
            pk.x = f2bf2(c2[0], c2[1]);
            pk.y = f2bf2(c2[2], c2[3]);
            *(uint2*)&outq[(size_t)lx * TT * TT + k0 + qd * 4] = pk;
        }

        c0 = n0; c1 = n1;
    }
}

// ---------------------------------------------------------------------------
// MFMA GEMM core (parameterized bm/bn), double-buffered LDS.
// ---------------------------------------------------------------------------
__device__ __forceinline__ void mfma_gemm_acc(
    const ushort* __restrict__ A, const ushort* __restrict__ B,
    f32x4 (&acc)[4][4], ushort* As, ushort* Bs, int bm, int bn)
{
    const int t = threadIdx.x;
    const int w = t >> 6, lane = t & 63, lx = lane & 15, quad = lane >> 4;
    const int wr = w >> 1, wc = w & 1;
    const int sr = t >> 1, sh = (t & 1) << 4;

    const ushort* Arow = A + (size_t)(bm * 128 + sr) * CC + sh;
    const ushort* Brow = B + (size_t)(bn * 128 + sr) * CC + sh;

    uint4 a0 = *(const uint4*)(Arow);
    uint4 a1 = *(const uint4*)(Arow + 8);
    uint4 b0 = *(const uint4*)(Brow);
    uint4 b1 = *(const uint4*)(Brow + 8);
    *(uint4*)&As[sr * 40 + sh]     = a0;
    *(uint4*)&As[sr * 40 + sh + 8] = a1;
    *(uint4*)&Bs[sr * 40 + sh]     = b0;
    *(uint4*)&Bs[sr * 40 + sh + 8] = b1;

    for (int kb = 0; kb < 24; kb++) {
        __syncthreads();
        const int cur = (kb & 1) * 5120, nxt = ((kb + 1) & 1) * 5120;
        if (kb < 23) {
            a0 = *(const uint4*)(Arow + (kb + 1) * 32);
            a1 = *(const uint4*)(Arow + (kb + 1) * 32 + 8);
            b0 = *(const uint4*)(Brow + (kb + 1) * 32);
            b1 = *(const uint4*)(Brow + (kb + 1) * 32 + 8);
        }
        bf16x8 af[4], bfr[4];
#pragma unroll
        for (int mt = 0; mt < 4; mt++)
            af[mt] = *(const bf16x8*)&As[cur + (wr * 64 + mt * 16 + lx) * 40 + quad * 8];
#pragma unroll
        for (int nt = 0; nt < 4; nt++)
            bfr[nt] = *(const bf16x8*)&Bs[cur + (wc * 64 + nt * 16 + lx) * 40 + quad * 8];
#pragma unroll
        for (int mt = 0; mt < 4; mt++)
#pragma unroll
            for (int nt = 0; nt < 4; nt++)
                acc[mt][nt] = MFMA16(af[mt], bfr[nt], acc[mt][nt]);
        if (kb < 23) {
            *(uint4*)&As[nxt + sr * 40 + sh]     = a0;
            *(uint4*)&As[nxt + sr * 40 + sh + 8] = a1;
            *(uint4*)&Bs[nxt + sr * 40 + sh]     = b0;
            *(uint4*)&Bs[nxt + sr * 40 + sh + 8] = b1;
        }
    }
}

// ---------------------------------------------------------------------------
// k1: cast5 ∪ adj(q<256). 9728 blocks, interleaved 15 cast : 4 adj (%19).
// ---------------------------------------------------------------------------
__global__ __launch_bounds__(256)
void cast_adj(const float* __restrict__ x,  const float* __restrict__ wq,
              const float* __restrict__ wk, const float* __restrict__ wv,
              const float* __restrict__ wp,
              ushort* __restrict__ xb,  ushort* __restrict__ wqb,
              ushort* __restrict__ wkb, ushort* __restrict__ wvb,
              ushort* __restrict__ wpb,
              const float* __restrict__ adj, const float* __restrict__ A1,
              const float* __restrict__ A2, const float* __restrict__ adjw_p,
              ushort* __restrict__ Fb)
{
    __shared__ float A1s[288];
    __shared__ float A2s[288];

    const int bid = blockIdx.x;
    const int g = bid / 19, r = bid % 19;

    if (r < 4) {
        const int idx = g * 4 + r;                 // 0..2047
        adj_body(adj, A1, A2, adjw_p, Fb, A1s, A2s, idx & 255, idx >> 8);
        return;
    }

    const int cidx = g * 15 + (r - 4);             // 0..7679
    const int bx = cidx % 1536, by = cidx / 1536;
    const float* src; ushort* dst; int n8;
    switch (by) {
      case 0:  src = x;  dst = xb;  n8 = 393216; break;
      case 1:  src = wq; dst = wqb; n8 = 73728;  break;
      case 2:  src = wk; dst = wkb; n8 = 73728;  break;
      case 3:  src = wv; dst = wvb; n8 = 73728;  break;
      default: src = wp; dst = wpb; n8 = 73728;  break;
    }
    int i = bx * 256 + threadIdx.x;
    if (i >= n8) return;
    float4 a = ((const float4*)src)[2 * i];
    float4 b = ((const float4*)src)[2 * i + 1];
    uint4 o;
    o.x = f2bf2(a.x, a.y);
    o.y = f2bf2(a.z, a.w);
    o.z = f2bf2(b.x, b.y);
    o.w = f2bf2(b.z, b.w);
    ((uint4*)dst)[i] = o;
}

// ---------------------------------------------------------------------------
// k2: qkv ∪ adj(q>=256). 2624 blocks, interleaved 9 qkv : 32 adj (%41).
// LDS overlaid: qkv uses all 40KB; adj aliases the first 2304B as floats.
// ---------------------------------------------------------------------------
__global__ __launch_bounds__(256)
void qkv_adj(const ushort* __restrict__ xb,
             const ushort* __restrict__ Wqb, const float* __restrict__ bq,
             const ushort* __restrict__ Wkb, const float* __restrict__ bk,
             const ushort* __restrict__ Wvb, const float* __restrict__ bv,
             ushort* __restrict__ Qb, ushort* __restrict__ Kb,
             ushort* __restrict__ VtB,
             const float* __restrict__ adj, const float* __restrict__ A1,
             const float* __restrict__ A2, const float* __restrict__ adjw_p,
             ushort* __restrict__ Fb)
{
    __shared__ __align__(16) ushort sh[20480];     // 40 KB union

    const int bid = blockIdx.x;
    const int g = bid / 41, r = bid % 41;

    if (r >= 9) {
        const int idx = g * 32 + (r - 9);          // 0..2047
        adj_body(adj, A1, A2, adjw_p, Fb,
                 (float*)sh, (float*)(sh + 576), 256 + (idx & 255), idx >> 8);
        return;
    }

    const int qidx = g * 9 + r;                    // 0..575
    const int bm = qidx % 32, bn = (qidx / 32) % 6, z = qidx / 192;

    ushort* As = sh;
    ushort* Bs = sh + 10240;
    const ushort* W   = (z == 0) ? Wqb : (z == 1) ? Wkb : Wvb;
    const float* bias = (z == 0) ? bq  : (z == 1) ? bk  : bv;

    f32x4 acc[4][4];
#pragma unroll
    for (int i = 0; i < 4; i++)
#pragma unroll
        for (int j = 0; j < 4; j++) acc[i][j] = (f32x4){0.f, 0.f, 0.f, 0.f};

    mfma_gemm_acc(xb, W, acc, As, Bs, bm, bn);

    const int t = threadIdx.x;
    const int w = t >> 6, lane = t & 63, lx = lane & 15, quad = lane >> 4;
    const int wr = w >> 1, wc = w & 1;

    float bvv[4];
#pragma unroll
    for (int nt = 0; nt < 4; nt++)
        bvv[nt] = bias[bn * 128 + wc * 64 + nt * 16 + lx];

    if (z < 2) {
        ushort* O = (z == 0) ? Qb : Kb;
#pragma unroll
        for (int mt = 0; mt < 4; mt++) {
            int m0 = bm * 128 + wr * 64 + mt * 16 + quad * 4;
            int bb = m0 >> 9, q = m0 & 511;
#pragma unroll
            for (int nt = 0; nt < 4; nt++) {
                int n = bn * 128 + wc * 64 + nt * 16 + lx;
                int hh = n >> 6, d = n & 63;
                size_t base = ((size_t)(bb * NH + hh) * TT + q) * HD + d;
#pragma unroll
                for (int i = 0; i < 4; i++)
                    O[base + (size_t)i * HD] = f2bf(acc[mt][nt][i] + bvv[nt]);
            }
        }
    } else {
#pragma unroll
        for (int mt = 0; mt < 4; mt++) {
            int m0 = bm * 128 + wr * 64 + mt * 16 + quad * 4;
            int bb = m0 >> 9, k = m0 & 511;
            int kt = k >> 6, kw = k & 63;
#pragma unroll
            for (int nt = 0; nt < 4; nt++) {
                int n = bn * 128 + wc * 64 + nt * 16 + lx;
                int hh = n >> 6, d = n & 63;
                uint2 pk;
                pk.x = f2bf2(acc[mt][nt][0] + bvv[nt], acc[mt][nt][1] + bvv[nt]);
                pk.y = f2bf2(acc[mt][nt][2] + bvv[nt], acc[mt][nt][3] + bvv[nt]);
                *(uint2*)&VtB[(size_t)((bb * NH + hh) * 8 + kt) * 4096 + d * 64 + kw] = pk;
            }
        }
    }
}

__global__ __launch_bounds__(256)
void proj_mfma(const ushort* __restrict__ y1, const ushort* __restrict__ Wpb,
               const float* __restrict__ bp, float* __restrict__ out)
{
    __shared__ ushort As[10240], Bs[10240];
    f32x4 acc[4][4];
#pragma unroll
    for (int i = 0; i < 4; i++)
#pragma unroll
        for (int j = 0; j < 4; j++) acc[i][j] = (f32x4){0.f, 0.f, 0.f, 0.f};

    mfma_gemm_acc(y1, Wpb, acc, As, Bs, blockIdx.x, blockIdx.y);

    const int t = threadIdx.x;
    const int w = t >> 6, lane = t & 63, lx = lane & 15, quad = lane >> 4;
    const int wr = w >> 1, wc = w & 1;
    const int bm = blockIdx.x, bn = blockIdx.y;
#pragma unroll
    for (int nt = 0; nt < 4; nt++) {
        int n = bn * 128 + wc * 64 + nt * 16 + lx;
        float bvv = bp[n];
#pragma unroll
        for (int mt = 0; mt < 4; mt++) {
            int m0 = bm * 128 + wr * 64 + mt * 16 + quad * 4;
#pragma unroll
            for (int i = 0; i < 4; i++)
                out[(size_t)(m0 + i) * CC + n] = acc[mt][nt][i] + bvv;
        }
    }
}

// ---------------------------------------------------------------------------
// flash_mfma v6 (unchanged from R6): contiguous per-head layouts + XCD swizzle.
// ---------------------------------------------------------------------------
__global__ __launch_bounds__(256)
void flash_mfma(const ushort* __restrict__ Qh, const ushort* __restrict__ Kh,
                const ushort* __restrict__ VtB, const ushort* __restrict__ Fb,
                const float* __restrict__ pad, ushort* __restrict__ y1)
{
    __shared__ ushort Ps[4][16][72];

    const int t = threadIdx.x, w = t >> 6, lane = t & 63;
    const int lx = lane & 15, quad = lane >> 4;

    const int id  = blockIdx.x + 8 * blockIdx.y + 96 * blockIdx.z;
    const int xcd = id & 7, j = id >> 3;
    const int pair = xcd * 12 + (j >> 3);
    const int qt  = j & 7;
    const int h   = pair % NH, b = pair / NH;

    const int q0 = qt * 64;
    const int bh = b * NH + h;

    const ushort* Qrow = Qh + ((size_t)bh * TT + q0 + w * 16 + lx) * HD + quad * 8;
    bf16x8 qa0 = *(const bf16x8*)Qrow;
    bf16x8 qa1 = *(const bf16x8*)(Qrow + 32);

    const float kq = 1.0f - pad[b * TT + q0 + w * 16 + lx];

    f32x4 o[4], o2[4];
#pragma unroll
    for (int i = 0; i < 4; i++) {
        o[i]  = (f32x4){0.f, 0.f, 0.f, 0.f};
        o2[i] = (f32x4){0.f, 0.f, 0.f, 0.f};
    }
    float ls = 0.f;

    const ushort* Frow  = Fb + (size_t)(bh * TT + q0 + w * 16 + lx) * TT + quad * 8;
    const float*  padk  = pad + b * TT;
    const ushort* Vbase = VtB + (size_t)bh * 8 * 4096;

    for (int ck = 0; ck < 8; ck++) {
        const int k0 = ck * 64;

        bf16x8 ka[4][2];
        float4 kp[4];
#pragma unroll
        for (int mt = 0; mt < 4; mt++) {
            const ushort* Krow = Kh + ((size_t)bh * TT + k0 + mt * 16 + lx) * HD + quad * 8;
            ka[mt][0] = *(const bf16x8*)Krow;
            ka[mt][1] = *(const bf16x8*)(Krow + 32);
            kp[mt] = *(const float4*)&padk[k0 + mt * 16 + quad * 4];
        }
        bf16x8 vb[4][2];
#pragma unroll
        for (int nt = 0; nt < 4; nt++) {
            const ushort* Vrow = Vbase + (size_t)ck * 4096 + (nt * 16 + lx) * 64 + quad * 8;
            vb[nt][0] = *(const bf16x8*)Vrow;
            vb[nt][1] = *(const bf16x8*)(Vrow + 32);
        }
        bf16x8 fa0 = *(const bf16x8*)(Frow + k0);
        bf16x8 fa1 = *(const bf16x8*)(Frow + k0 + 32);

        f32x4 st[4];
#pragma unroll
        for (int mt = 0; mt < 4; mt++) {
            f32x4 z = (f32x4){0.f, 0.f, 0.f, 0.f};
            z = MFMA16(ka[mt][0], qa0, z);
            z = MFMA16(ka[mt][1], qa1, z);
            st[mt] = z;
        }

#pragma unroll
        for (int mt = 0; mt < 4; mt++) {
            float pv[4];
#pragma unroll
            for (int i = 0; i < 4; i++) {
                float kpad = ((const float*)&kp[mt])[i];
                float p = __builtin_amdgcn_exp2f(st[mt][i] * 0.18033688011112042f);
                p = (kpad != 0.0f) ? 0.0f : p;
                p = (kq == 0.0f) ? 1.0f : p;
                pv[i] = p; ls += p;
            }
            uint2 pk;
            pk.x = f2bf2(pv[0], pv[1]);
            pk.y = f2bf2(pv[2], pv[3]);
            *(uint2*)&Ps[w][lx][mt * 16 + quad * 4] = pk;
        }
        asm volatile("s_waitcnt lgkmcnt(0)" ::: "memory");
        bf16x8 pa0 = *(const bf16x8*)&Ps[w][lx][quad * 8];
        bf16x8 pa1 = *(const bf16x8*)&Ps[w][lx][32 + quad * 8];

#pragma unroll
        for (int nt = 0; nt < 4; nt++) {
            o[nt]  = MFMA16(pa0, vb[nt][0], o[nt]);
            o[nt]  = MFMA16(pa1, vb[nt][1], o[nt]);
            o2[nt] = MFMA16(fa0, vb[nt][0], o2[nt]);
            o2[nt] = MFMA16(fa1, vb[nt][1], o2[nt]);
        }
    }
    ls += __shfl_xor(ls, 16, 64);
    ls += __shfl_xor(ls, 32, 64);
    float inv[4];
#pragma unroll
    for (int i = 0; i < 4; i++)
        inv[i] = 1.0f / __shfl(ls, quad * 4 + i, 16);
#pragma unroll
    for (int nt = 0; nt < 4; nt++)
#pragma unroll
        for (int i = 0; i < 4; i++)
            y1[(size_t)(b * TT + q0 + w * 16 + quad * 4 + i) * CC + h * HD + nt * 16 + lx] =
                f2bf(o[nt][i] * inv[i] + o2[nt][i]);
}

// ---------------------------------------------------------------------------
extern "C" void kernel_launch(void* const* d_in, const int* in_sizes, int n_in,
                              void* d_out, int out_size, void* d_ws, size_t ws_size,
                              hipStream_t stream)
{
    const float* x    = (const float*)d_in[0];
    const float* pad  = (const float*)d_in[1];
    const float* adj  = (const float*)d_in[2];
    const float* Wq   = (const float*)d_in[3];
    const float* bq   = (const float*)d_in[4];
    const float* Wk   = (const float*)d_in[5];
    const float* bk   = (const float*)d_in[6];
    const float* Wv   = (const float*)d_in[7];
    const float* bv   = (const float*)d_in[8];
    const float* Wp   = (const float*)d_in[9];
    const float* bp   = (const float*)d_in[10];
    const float* A1   = (const float*)d_in[11];
    const float* A2   = (const float*)d_in[12];
    const float* adjw = (const float*)d_in[13];

    ushort* ws  = (ushort*)d_ws;
    ushort* Fb  = ws;                     // 25,165,824 (B*H*T*T)
    ushort* Qb  = Fb + 25165824;          // 3,145,728 each
    ushort* Kb  = Qb + 3145728;
    ushort* Vt  = Kb + 3145728;
    ushort* y1  = Vt + 3145728;
    ushort* xb  = y1 + 3145728;
    ushort* Wqb = xb + 3145728;           // 589,824 each
    ushort* Wkb = Wqb + 589824;
    ushort* Wvb = Wkb + 589824;
    ushort* Wpb = Wvb + 589824;
    float*  out = (float*)d_out;

    // k1: cast5 (7680) ∪ adj q<256 (2048), interleaved 15:4
    cast_adj<<<9728, 256, 0, stream>>>(x, Wq, Wk, Wv, Wp,
                                       xb, Wqb, Wkb, Wvb, Wpb,
                                       adj, A1, A2, adjw, Fb);
    // k2: qkv (576) ∪ adj q>=256 (2048), interleaved 9:32
    qkv_adj<<<2624, 256, 0, stream>>>(xb, Wqb, bq, Wkb, bk, Wvb, bv,
                                      Qb, Kb, Vt,
                                      adj, A1, A2, adjw, Fb);
    flash_mfma<<<dim3(8, 12, 8), 256, 0, stream>>>(Qb, Kb, Vt, Fb, pad, y1);
    proj_mfma<<<dim3(32, 6), 256, 0, stream>>>(y1, Wpb, bp, out);
}

// Round 9
// 301.248 us; speedup vs baseline: 1.0707x; 1.0707x over previous
//
#include <hip/hip_runtime.h>
#include <math.h>

#define TT 512
#define CC 768
#define NH 12
#define HD 64
#define ADJF 12

typedef __attribute__((ext_vector_type(8))) short bf16x8;
typedef __attribute__((ext_vector_type(4))) short bf16x4;
typedef __attribute__((ext_vector_type(4))) float f32x4;
typedef __attribute__((ext_vector_type(2))) float f32x2v;
typedef __attribute__((ext_vector_type(2))) __bf16 bf16x2v;

__device__ __forceinline__ ushort f2bf(float x) {
    union { __bf16 b; ushort u; } c; c.b = (__bf16)x; return c.u;
}
__device__ __forceinline__ unsigned f2bf2(float lo, float hi) {
    f32x2v s; s[0] = lo; s[1] = hi;
    union { bf16x2v b; unsigned u; } c;
    c.b = __builtin_convertvector(s, bf16x2v);
    return c.u;
}

#define MFMA16(a, b, c) __builtin_amdgcn_mfma_f32_16x16x32_bf16((a), (b), (c), 0, 0, 0)

__device__ __forceinline__ f32x4 MFMA16K(bf16x4 a, bf16x4 b, f32x4 c) {
#if __has_builtin(__builtin_amdgcn_mfma_f32_16x16x16bf16_1k)
    return __builtin_amdgcn_mfma_f32_16x16x16bf16_1k(a, b, c, 0, 0, 0);
#else
    f32x4 d;
    asm("v_mfma_f32_16x16x16_bf16 %0, %1, %2, %3"
        : "=v"(d) : "v"(a), "v"(b), "v"(c));
    return d;
#endif
}

// ---------------------------------------------------------------------------
// cast5: bf16 copies of x and the four weight matrices.
// ---------------------------------------------------------------------------
__global__ __launch_bounds__(256)
void cast5(const float* __restrict__ x,  const float* __restrict__ wq,
           const float* __restrict__ wk, const float* __restrict__ wv,
           const float* __restrict__ wp,
           ushort* __restrict__ xb,  ushort* __restrict__ wqb,
           ushort* __restrict__ wkb, ushort* __restrict__ wvb,
           ushort* __restrict__ wpb)
{
    const float* src; ushort* dst; int n8;
    switch (blockIdx.y) {
      case 0:  src = x;  dst = xb;  n8 = 393216; break;
      case 1:  src = wq; dst = wqb; n8 = 73728;  break;
      case 2:  src = wk; dst = wkb; n8 = 73728;  break;
      case 3:  src = wv; dst = wvb; n8 = 73728;  break;
      default: src = wp; dst = wpb; n8 = 73728;  break;
    }
    int i = blockIdx.x * 256 + threadIdx.x;
    if (i >= n8) return;
    float4 a = ((const float4*)src)[2 * i];
    float4 b = ((const float4*)src)[2 * i + 1];
    uint4 o;
    o.x = f2bf2(a.x, a.y);
    o.y = f2bf2(a.z, a.w);
    o.z = f2bf2(b.x, b.y);
    o.w = f2bf2(b.z, b.w);
    ((uint4*)dst)[i] = o;
}

// ---------------------------------------------------------------------------
// MFMA GEMM core, double-buffered LDS: C[M,N] = A[M,K] @ B[N,K]^T.
// ---------------------------------------------------------------------------
__device__ __forceinline__ void mfma_gemm_acc(
    const ushort* __restrict__ A, const ushort* __restrict__ B,
    f32x4 (&acc)[4][4], ushort* As, ushort* Bs)
{
    const int t = threadIdx.x;
    const int bm = blockIdx.x, bn = blockIdx.y;
    const int w = t >> 6, lane = t & 63, lx = lane & 15, quad = lane >> 4;
    const int wr = w >> 1, wc = w & 1;
    const int sr = t >> 1, sh = (t & 1) << 4;

    const ushort* Arow = A + (size_t)(bm * 128 + sr) * CC + sh;
    const ushort* Brow = B + (size_t)(bn * 128 + sr) * CC + sh;

    uint4 a0 = *(const uint4*)(Arow);
    uint4 a1 = *(const uint4*)(Arow + 8);
    uint4 b0 = *(const uint4*)(Brow);
    uint4 b1 = *(const uint4*)(Brow + 8);
    *(uint4*)&As[sr * 40 + sh]     = a0;
    *(uint4*)&As[sr * 40 + sh + 8] = a1;
    *(uint4*)&Bs[sr * 40 + sh]     = b0;
    *(uint4*)&Bs[sr * 40 + sh + 8] = b1;

    for (int kb = 0; kb < 24; kb++) {
        __syncthreads();
        const int cur = (kb & 1) * 5120, nxt = ((kb + 1) & 1) * 5120;
        if (kb < 23) {
            a0 = *(const uint4*)(Arow + (kb + 1) * 32);
            a1 = *(const uint4*)(Arow + (kb + 1) * 32 + 8);
            b0 = *(const uint4*)(Brow + (kb + 1) * 32);
            b1 = *(const uint4*)(Brow + (kb + 1) * 32 + 8);
        }
        bf16x8 af[4], bfr[4];
#pragma unroll
        for (int mt = 0; mt < 4; mt++)
            af[mt] = *(const bf16x8*)&As[cur + (wr * 64 + mt * 16 + lx) * 40 + quad * 8];
#pragma unroll
        for (int nt = 0; nt < 4; nt++)
            bfr[nt] = *(const bf16x8*)&Bs[cur + (wc * 64 + nt * 16 + lx) * 40 + quad * 8];
#pragma unroll
        for (int mt = 0; mt < 4; mt++)
#pragma unroll
            for (int nt = 0; nt < 4; nt++)
                acc[mt][nt] = MFMA16(af[mt], bfr[nt], acc[mt][nt]);
        if (kb < 23) {
            *(uint4*)&As[nxt + sr * 40 + sh]     = a0;
            *(uint4*)&As[nxt + sr * 40 + sh + 8] = a1;
            *(uint4*)&Bs[nxt + sr * 40 + sh]     = b0;
            *(uint4*)&Bs[nxt + sr * 40 + sh + 8] = b1;
        }
    }
}

// ---------------------------------------------------------------------------
// qkv: z=0 -> Q per-head [B,H,T,HD]; z=1 -> K per-head; z=2 -> V k-tiled.
// ---------------------------------------------------------------------------
__global__ __launch_bounds__(256)
void qkv_mfma(const ushort* __restrict__ xb,
              const ushort* __restrict__ Wqb, const float* __restrict__ bq,
              const ushort* __restrict__ Wkb, const float* __restrict__ bk,
              const ushort* __restrict__ Wvb, const float* __restrict__ bv,
              ushort* __restrict__ Qb, ushort* __restrict__ Kb,
              ushort* __restrict__ VtB)
{
    __shared__ ushort As[10240], Bs[10240];
    const int z = blockIdx.z;
    const ushort* W   = (z == 0) ? Wqb : (z == 1) ? Wkb : Wvb;
    const float* bias = (z == 0) ? bq  : (z == 1) ? bk  : bv;

    f32x4 acc[4][4];
#pragma unroll
    for (int i = 0; i < 4; i++)
#pragma unroll
        for (int j = 0; j < 4; j++) acc[i][j] = (f32x4){0.f, 0.f, 0.f, 0.f};

    mfma_gemm_acc(xb, W, acc, As, Bs);

    const int t = threadIdx.x;
    const int w = t >> 6, lane = t & 63, lx = lane & 15, quad = lane >> 4;
    const int wr = w >> 1, wc = w & 1;
    const int bm = blockIdx.x, bn = blockIdx.y;

    float bvv[4];
#pragma unroll
    for (int nt = 0; nt < 4; nt++)
        bvv[nt] = bias[bn * 128 + wc * 64 + nt * 16 + lx];

    if (z < 2) {
        ushort* O = (z == 0) ? Qb : Kb;
#pragma unroll
        for (int mt = 0; mt < 4; mt++) {
            int m0 = bm * 128 + wr * 64 + mt * 16 + quad * 4;
            int bb = m0 >> 9, q = m0 & 511;
#pragma unroll
            for (int nt = 0; nt < 4; nt++) {
                int n = bn * 128 + wc * 64 + nt * 16 + lx;
                int hh = n >> 6, d = n & 63;
                size_t base = ((size_t)(bb * NH + hh) * TT + q) * HD + d;
#pragma unroll
                for (int i = 0; i < 4; i++)
                    O[base + (size_t)i * HD] = f2bf(acc[mt][nt][i] + bvv[nt]);
            }
        }
    } else {
#pragma unroll
        for (int mt = 0; mt < 4; mt++) {
            int m0 = bm * 128 + wr * 64 + mt * 16 + quad * 4;
            int bb = m0 >> 9, k = m0 & 511;
            int kt = k >> 6, kw = k & 63;
#pragma unroll
            for (int nt = 0; nt < 4; nt++) {
                int n = bn * 128 + wc * 64 + nt * 16 + lx;
                int hh = n >> 6, d = n & 63;
                uint2 pk;
                pk.x = f2bf2(acc[mt][nt][0] + bvv[nt], acc[mt][nt][1] + bvv[nt]);
                pk.y = f2bf2(acc[mt][nt][2] + bvv[nt], acc[mt][nt][3] + bvv[nt]);
                *(uint2*)&VtB[(size_t)((bb * NH + hh) * 8 + kt) * 4096 + d * 64 + kw] = pk;
            }
        }
    }
}

__global__ __launch_bounds__(256)
void proj_mfma(const ushort* __restrict__ y1, const ushort* __restrict__ Wpb,
               const float* __restrict__ bp, float* __restrict__ out)
{
    __shared__ ushort As[10240], Bs[10240];
    f32x4 acc[4][4];
#pragma unroll
    for (int i = 0; i < 4; i++)
#pragma unroll
        for (int j = 0; j < 4; j++) acc[i][j] = (f32x4){0.f, 0.f, 0.f, 0.f};

    mfma_gemm_acc(y1, Wpb, acc, As, Bs);

    const int t = threadIdx.x;
    const int w = t >> 6, lane = t & 63, lx = lane & 15, quad = lane >> 4;
    const int wr = w >> 1, wc = w & 1;
    const int bm = blockIdx.x, bn = blockIdx.y;
#pragma unroll
    for (int nt = 0; nt < 4; nt++) {
        int n = bn * 128 + wc * 64 + nt * 16 + lx;
        float bvv = bp[n];
#pragma unroll
        for (int mt = 0; mt < 4; mt++) {
            int m0 = bm * 128 + wr * 64 + mt * 16 + quad * 4;
#pragma unroll
            for (int i = 0; i < 4; i++)
                out[(size_t)(m0 + i) * CC + n] = acc[mt][nt][i] + bvv;
        }
    }
}

// ---------------------------------------------------------------------------
// adj_f_mfma v5: register-dataflow core + fixed memory endpoints, using ONLY
// HW-verified DMA configs.
//  Loads: 3x global_load_lds size=4 (m03-verified: dest = base + lane*4),
//  64 lanes x 4B x 3 chunks = the wave's contiguous 768B iteration region.
//  Per-wave double buffer, issued 1 iter ahead; vmcnt(0)+sched_barrier at
//  iter top. The compiler cannot sink a DMA (R5 lesson).
//  Stores: c2 -> padded LDS tile Fs[12][516]; one barrier; 12 coalesced 1KB
//  row stores (was 32 instrs scattering 12 x 8B at 512KB stride each).
// R8's size=12 DMA (unmeasured lane-stride) was the correctness bug; gone.
// ---------------------------------------------------------------------------
__device__ __forceinline__ float gelu_s(float x) {
    float x2 = x * x;
    float u  = __builtin_fmaf(x2, 0.025f, -0.166666666666667f);
    u        = __builtin_fmaf(x2, u, 1.0f);
    float er = 0.79788456080286536f * x * u;
    return 0.5f * x * (1.0f + er);
}

__global__ __launch_bounds__(256)
void adj_f_mfma(const float* __restrict__ adj, const float* __restrict__ A1,
                const float* __restrict__ A2, const float* __restrict__ adjw_p,
                ushort* __restrict__ Fb)
{
    __shared__ float A1s[288];
    __shared__ float A2s[288];
    __shared__ __align__(16) float adjS[4][2][192];   // per-wave dbuf, 768B each
    __shared__ __align__(8)  ushort Fs[12 * 516];     // F tile [h][k], pad 516

    const int t = threadIdx.x;
    for (int i = t; i < 288; i += 256) { A1s[i] = A1[i]; A2s[i] = A2[i]; }
    __syncthreads();

    const int w = t >> 6, lane = t & 63, lx = lane & 15, qd = lane >> 4;
    const int q = blockIdx.x, b = blockIdx.y;
    const float adjw = adjw_p[0];

    union { bf16x8 v; ushort u[8]; } b1a, b1b;
#pragma unroll
    for (int j = 0; j < 8; j++) {
        int f = qd * 8 + j;
        b1a.u[j] = (f < 12) ? f2bf(A1s[lx * 12 + f]) : (ushort)0;
        b1b.u[j] = (lx < 8 && f < 12) ? f2bf(A1s[(16 + lx) * 12 + f]) : (ushort)0;
    }
    union { bf16x4 v; ushort u[4]; } B2lo, B2hi;
#pragma unroll
    for (int j = 0; j < 4; j++) {
        int elo = qd * 4 + j;
        int ehi = 16 + qd * 4 + j;
        B2lo.u[j] = (lx < 12) ? f2bf(adjw * A2s[lx * 24 + elo]) : (ushort)0;
        B2hi.u[j] = (lx < 12 && ehi < 24) ? f2bf(adjw * A2s[lx * 24 + ehi]) : (ushort)0;
    }

    const size_t prow = ((size_t)b * TT + q) * TT;

#if __has_builtin(__builtin_amdgcn_global_load_lds)
    // wave w's iter-0 region: rows [w*16, w*16+16) = 768B contiguous
    const char* gbase = (const char*)(adj + (prow + w * 16) * ADJF);
#pragma unroll
    for (int c = 0; c < 3; c++)
        __builtin_amdgcn_global_load_lds(
            (const __attribute__((address_space(1))) void*)(gbase + c * 256 + lane * 4),
            (__attribute__((address_space(3))) void*)&adjS[w][0][c * 64], 4, 0, 0);
#endif

    for (int it = 0; it < 8; it++) {
        const int k0 = it * 64 + w * 16;
        const int buf = it & 1;

#if __has_builtin(__builtin_amdgcn_global_load_lds)
        asm volatile("s_waitcnt vmcnt(0)" ::: "memory");
        __builtin_amdgcn_sched_barrier(0);
        if (it < 7) {
            const char* gn = gbase + (size_t)(it + 1) * 3072;   // +64 rows
#pragma unroll
            for (int c = 0; c < 3; c++)
                __builtin_amdgcn_global_load_lds(
                    (const __attribute__((address_space(1))) void*)(gn + c * 256 + lane * 4),
                    (__attribute__((address_space(3))) void*)&adjS[w][buf ^ 1][c * 64], 4, 0, 0);
        }
        const float* L = &adjS[w][buf][lx * 12];
#else
        const float* L = adj + (prow + k0 + lx) * ADJF;
#endif

        union { bf16x8 v; unsigned u[4]; } afr;
        if (qd == 0) {
            float4 u0 = *(const float4*)(L);
            float4 u1 = *(const float4*)(L + 4);
            afr.u[0] = f2bf2(u0.x, u0.y); afr.u[1] = f2bf2(u0.z, u0.w);
            afr.u[2] = f2bf2(u1.x, u1.y); afr.u[3] = f2bf2(u1.z, u1.w);
        } else if (qd == 1) {
            float4 u0 = *(const float4*)(L + 8);
            afr.u[0] = f2bf2(u0.x, u0.y); afr.u[1] = f2bf2(u0.z, u0.w);
            afr.u[2] = 0; afr.u[3] = 0;
        } else {
            afr.u[0] = 0; afr.u[1] = 0; afr.u[2] = 0; afr.u[3] = 0;
        }

        f32x4 zz = (f32x4){0.f, 0.f, 0.f, 0.f};
        f32x4 c1a = MFMA16(b1a.v, afr.v, zz);
        f32x4 c1b = MFMA16(b1b.v, afr.v, zz);

        union { bf16x4 v; unsigned u[2]; } ga, gb;
        ga.u[0] = f2bf2(gelu_s(c1a[0]), gelu_s(c1a[1]));
        ga.u[1] = f2bf2(gelu_s(c1a[2]), gelu_s(c1a[3]));
        gb.u[0] = f2bf2(gelu_s(c1b[0]), gelu_s(c1b[1]));
        gb.u[1] = f2bf2(gelu_s(c1b[2]), gelu_s(c1b[3]));

        f32x4 c2 = MFMA16K(ga.v, B2lo.v, MFMA16K(gb.v, B2hi.v, zz));

        if (lx < 12) {
            uint2 pk;
            pk.x = f2bf2(c2[0], c2[1]);
            pk.y = f2bf2(c2[2], c2[3]);
            *(uint2*)&Fs[lx * 516 + k0 + qd * 4] = pk;
        }
    }

    __syncthreads();
    // coalesced writeout: 12 rows x 1KB, 256 threads x 4B each
    ushort* outb = Fb + (size_t)b * NH * TT * TT + (size_t)q * TT;
#pragma unroll
    for (int h = 0; h < NH; h++) {
        unsigned v = *(const unsigned*)&Fs[h * 516 + t * 2];
        *(unsigned*)&outb[(size_t)h * TT * TT + t * 2] = v;
    }
}

// ---------------------------------------------------------------------------
// flash_mfma v6 (unchanged): contiguous per-head layouts + XCD swizzle.
// ---------------------------------------------------------------------------
__global__ __launch_bounds__(256)
void flash_mfma(const ushort* __restrict__ Qh, const ushort* __restrict__ Kh,
                const ushort* __restrict__ VtB, const ushort* __restrict__ Fb,
                const float* __restrict__ pad, ushort* __restrict__ y1)
{
    __shared__ ushort Ps[4][16][72];

    const int t = threadIdx.x, w = t >> 6, lane = t & 63;
    const int lx = lane & 15, quad = lane >> 4;

    const int id  = blockIdx.x + 8 * blockIdx.y + 96 * blockIdx.z;
    const int xcd = id & 7, j = id >> 3;
    const int pair = xcd * 12 + (j >> 3);
    const int qt  = j & 7;
    const int h   = pair % NH, b = pair / NH;

    const int q0 = qt * 64;
    const int bh = b * NH + h;

    const ushort* Qrow = Qh + ((size_t)bh * TT + q0 + w * 16 + lx) * HD + quad * 8;
    bf16x8 qa0 = *(const bf16x8*)Qrow;
    bf16x8 qa1 = *(const bf16x8*)(Qrow + 32);

    const float kq = 1.0f - pad[b * TT + q0 + w * 16 + lx];

    f32x4 o[4], o2[4];
#pragma unroll
    for (int i = 0; i < 4; i++) {
        o[i]  = (f32x4){0.f, 0.f, 0.f, 0.f};
        o2[i] = (f32x4){0.f, 0.f, 0.f, 0.f};
    }
    float ls = 0.f;

    const ushort* Frow  = Fb + (size_t)(bh * TT + q0 + w * 16 + lx) * TT + quad * 8;
    const float*  padk  = pad + b * TT;
    const ushort* Vbase = VtB + (size_t)bh * 8 * 4096;

    for (int ck = 0; ck < 8; ck++) {
        const int k0 = ck * 64;

        bf16x8 ka[4][2];
        float4 kp[4];
#pragma unroll
        for (int mt = 0; mt < 4; mt++) {
            const ushort* Krow = Kh + ((size_t)bh * TT + k0 + mt * 16 + lx) * HD + quad * 8;
            ka[mt][0] = *(const bf16x8*)Krow;
            ka[mt][1] = *(const bf16x8*)(Krow + 32);
            kp[mt] = *(const float4*)&padk[k0 + mt * 16 + quad * 4];
        }
        bf16x8 vb[4][2];
#pragma unroll
        for (int nt = 0; nt < 4; nt++) {
            const ushort* Vrow = Vbase + (size_t)ck * 4096 + (nt * 16 + lx) * 64 + quad * 8;
            vb[nt][0] = *(const bf16x8*)Vrow;
            vb[nt][1] = *(const bf16x8*)(Vrow + 32);
        }
        bf16x8 fa0 = *(const bf16x8*)(Frow + k0);
        bf16x8 fa1 = *(const bf16x8*)(Frow + k0 + 32);

        f32x4 st[4];
#pragma unroll
        for (int mt = 0; mt < 4; mt++) {
            f32x4 z = (f32x4){0.f, 0.f, 0.f, 0.f};
            z = MFMA16(ka[mt][0], qa0, z);
            z = MFMA16(ka[mt][1], qa1, z);
            st[mt] = z;
        }

#pragma unroll
        for (int mt = 0; mt < 4; mt++) {
            float pv[4];
#pragma unroll
            for (int i = 0; i < 4; i++) {
                float kpad = ((const float*)&kp[mt])[i];
                float p = __builtin_amdgcn_exp2f(st[mt][i] * 0.18033688011112042f);
                p = (kpad != 0.0f) ? 0.0f : p;
                p = (kq == 0.0f) ? 1.0f : p;
                pv[i] = p; ls += p;
            }
            uint2 pk;
            pk.x = f2bf2(pv[0], pv[1]);
            pk.y = f2bf2(pv[2], pv[3]);
            *(uint2*)&Ps[w][lx][mt * 16 + quad * 4] = pk;
        }
        asm volatile("s_waitcnt lgkmcnt(0)" ::: "memory");
        bf16x8 pa0 = *(const bf16x8*)&Ps[w][lx][quad * 8];
        bf16x8 pa1 = *(const bf16x8*)&Ps[w][lx][32 + quad * 8];

#pragma unroll
        for (int nt = 0; nt < 4; nt++) {
            o[nt]  = MFMA16(pa0, vb[nt][0], o[nt]);
            o[nt]  = MFMA16(pa1, vb[nt][1], o[nt]);
            o2[nt] = MFMA16(fa0, vb[nt][0], o2[nt]);
            o2[nt] = MFMA16(fa1, vb[nt][1], o2[nt]);
        }
    }
    ls += __shfl_xor(ls, 16, 64);
    ls += __shfl_xor(ls, 32, 64);
    float inv[4];
#pragma unroll
    for (int i = 0; i < 4; i++)
        inv[i] = 1.0f / __shfl(ls, quad * 4 + i, 16);
#pragma unroll
    for (int nt = 0; nt < 4; nt++)
#pragma unroll
        for (int i = 0; i < 4; i++)
            y1[(size_t)(b * TT + q0 + w * 16 + quad * 4 + i) * CC + h * HD + nt * 16 + lx] =
                f2bf(o[nt][i] * inv[i] + o2[nt][i]);
}

// ---------------------------------------------------------------------------
extern "C" void kernel_launch(void* const* d_in, const int* in_sizes, int n_in,
                              void* d_out, int out_size, void* d_ws, size_t ws_size,
                              hipStream_t stream)
{
    const float* x    = (const float*)d_in[0];
    const float* pad  = (const float*)d_in[1];
    const float* adj  = (const float*)d_in[2];
    const float* Wq   = (const float*)d_in[3];
    const float* bq   = (const float*)d_in[4];
    const float* Wk   = (const float*)d_in[5];
    const float* bk   = (const float*)d_in[6];
    const float* Wv   = (const float*)d_in[7];
    const float* bv   = (const float*)d_in[8];
    const float* Wp   = (const float*)d_in[9];
    const float* bp   = (const float*)d_in[10];
    const float* A1   = (const float*)d_in[11];
    const float* A2   = (const float*)d_in[12];
    const float* adjw = (const float*)d_in[13];

    ushort* ws  = (ushort*)d_ws;
    ushort* Fb  = ws;                     // 25,165,824 (B*H*T*T)
    ushort* Qb  = Fb + 25165824;          // 3,145,728 each
    ushort* Kb  = Qb + 3145728;
    ushort* Vt  = Kb + 3145728;
    ushort* y1  = Vt + 3145728;
    ushort* xb  = y1 + 3145728;
    ushort* Wqb = xb + 3145728;           // 589,824 each
    ushort* Wkb = Wqb + 589824;
    ushort* Wvb = Wkb + 589824;
    ushort* Wpb = Wvb + 589824;
    float*  out = (float*)d_out;

    cast5<<<dim3(1536, 5), 256, 0, stream>>>(x, Wq, Wk, Wv, Wp,
                                             xb, Wqb, Wkb, Wvb, Wpb);
    qkv_mfma<<<dim3(32, 6, 3), 256, 0, stream>>>(xb, Wqb, bq, Wkb, bk, Wvb, bv,
                                                 Qb, Kb, Vt);
    adj_f_mfma<<<dim3(512, 8), 256, 0, stream>>>(adj, A1, A2, adjw, Fb);
    flash_mfma<<<dim3(8, 12, 8), 256, 0, stream>>>(Qb, Kb, Vt, Fb, pad, y1);
    proj_mfma<<<dim3(32, 6), 256, 0, stream>>>(y1, Wpb, bp, out);
}

// Round 10
// 297.896 us; speedup vs baseline: 1.0828x; 1.0113x over previous
//
#include <hip/hip_runtime.h>
#include <math.h>

#define TT 512
#define CC 768
#define NH 12
#define HD 64
#define ADJF 12

typedef __attribute__((ext_vector_type(8))) short bf16x8;
typedef __attribute__((ext_vector_type(4))) short bf16x4;
typedef __attribute__((ext_vector_type(4))) float f32x4;
typedef __attribute__((ext_vector_type(2))) float f32x2v;
typedef __attribute__((ext_vector_type(2))) __bf16 bf16x2v;

__device__ __forceinline__ ushort f2bf(float x) {
    union { __bf16 b; ushort u; } c; c.b = (__bf16)x; return c.u;
}
__device__ __forceinline__ unsigned f2bf2(float lo, float hi) {
    f32x2v s; s[0] = lo; s[1] = hi;
    union { bf16x2v b; unsigned u; } c;
    c.b = __builtin_convertvector(s, bf16x2v);
    return c.u;
}

#define MFMA16(a, b, c) __builtin_amdgcn_mfma_f32_16x16x32_bf16((a), (b), (c), 0, 0, 0)

__device__ __forceinline__ f32x4 MFMA16K(bf16x4 a, bf16x4 b, f32x4 c) {
#if __has_builtin(__builtin_amdgcn_mfma_f32_16x16x16bf16_1k)
    return __builtin_amdgcn_mfma_f32_16x16x16bf16_1k(a, b, c, 0, 0, 0);
#else
    f32x4 d;
    asm("v_mfma_f32_16x16x16_bf16 %0, %1, %2, %3"
        : "=v"(d) : "v"(a), "v"(b), "v"(c));
    return d;
#endif
}

// ---------------------------------------------------------------------------
// cast5: bf16 copies of x and the four weight matrices.
// ---------------------------------------------------------------------------
__global__ __launch_bounds__(256)
void cast5(const float* __restrict__ x,  const float* __restrict__ wq,
           const float* __restrict__ wk, const float* __restrict__ wv,
           const float* __restrict__ wp,
           ushort* __restrict__ xb,  ushort* __restrict__ wqb,
           ushort* __restrict__ wkb, ushort* __restrict__ wvb,
           ushort* __restrict__ wpb)
{
    const float* src; ushort* dst; int n8;
    switch (blockIdx.y) {
      case 0:  src = x;  dst = xb;  n8 = 393216; break;
      case 1:  src = wq; dst = wqb; n8 = 73728;  break;
      case 2:  src = wk; dst = wkb; n8 = 73728;  break;
      case 3:  src = wv; dst = wvb; n8 = 73728;  break;
      default: src = wp; dst = wpb; n8 = 73728;  break;
    }
    int i = blockIdx.x * 256 + threadIdx.x;
    if (i >= n8) return;
    float4 a = ((const float4*)src)[2 * i];
    float4 b = ((const float4*)src)[2 * i + 1];
    uint4 o;
    o.x = f2bf2(a.x, a.y);
    o.y = f2bf2(a.z, a.w);
    o.z = f2bf2(b.x, b.y);
    o.w = f2bf2(b.z, b.w);
    ((uint4*)dst)[i] = o;
}

// ---------------------------------------------------------------------------
// MFMA GEMM core, double-buffered LDS: C[M,N] = A[M,K] @ B[N,K]^T.
// ---------------------------------------------------------------------------
__device__ __forceinline__ void mfma_gemm_acc(
    const ushort* __restrict__ A, const ushort* __restrict__ B,
    f32x4 (&acc)[4][4], ushort* As, ushort* Bs)
{
    const int t = threadIdx.x;
    const int bm = blockIdx.x, bn = blockIdx.y;
    const int w = t >> 6, lane = t & 63, lx = lane & 15, quad = lane >> 4;
    const int wr = w >> 1, wc = w & 1;
    const int sr = t >> 1, sh = (t & 1) << 4;

    const ushort* Arow = A + (size_t)(bm * 128 + sr) * CC + sh;
    const ushort* Brow = B + (size_t)(bn * 128 + sr) * CC + sh;

    uint4 a0 = *(const uint4*)(Arow);
    uint4 a1 = *(const uint4*)(Arow + 8);
    uint4 b0 = *(const uint4*)(Brow);
    uint4 b1 = *(const uint4*)(Brow + 8);
    *(uint4*)&As[sr * 40 + sh]     = a0;
    *(uint4*)&As[sr * 40 + sh + 8] = a1;
    *(uint4*)&Bs[sr * 40 + sh]     = b0;
    *(uint4*)&Bs[sr * 40 + sh + 8] = b1;

    for (int kb = 0; kb < 24; kb++) {
        __syncthreads();
        const int cur = (kb & 1) * 5120, nxt = ((kb + 1) & 1) * 5120;
        if (kb < 23) {
            a0 = *(const uint4*)(Arow + (kb + 1) * 32);
            a1 = *(const uint4*)(Arow + (kb + 1) * 32 + 8);
            b0 = *(const uint4*)(Brow + (kb + 1) * 32);
            b1 = *(const uint4*)(Brow + (kb + 1) * 32 + 8);
        }
        bf16x8 af[4], bfr[4];
#pragma unroll
        for (int mt = 0; mt < 4; mt++)
            af[mt] = *(const bf16x8*)&As[cur + (wr * 64 + mt * 16 + lx) * 40 + quad * 8];
#pragma unroll
        for (int nt = 0; nt < 4; nt++)
            bfr[nt] = *(const bf16x8*)&Bs[cur + (wc * 64 + nt * 16 + lx) * 40 + quad * 8];
#pragma unroll
        for (int mt = 0; mt < 4; mt++)
#pragma unroll
            for (int nt = 0; nt < 4; nt++)
                acc[mt][nt] = MFMA16(af[mt], bfr[nt], acc[mt][nt]);
        if (kb < 23) {
            *(uint4*)&As[nxt + sr * 40 + sh]     = a0;
            *(uint4*)&As[nxt + sr * 40 + sh + 8] = a1;
            *(uint4*)&Bs[nxt + sr * 40 + sh]     = b0;
            *(uint4*)&Bs[nxt + sr * 40 + sh + 8] = b1;
        }
    }
}

// ---------------------------------------------------------------------------
// qkv: z=0 -> Q per-head [B,H,T,HD]; z=1 -> K per-head; z=2 -> V k-tiled.
// ---------------------------------------------------------------------------
__global__ __launch_bounds__(256)
void qkv_mfma(const ushort* __restrict__ xb,
              const ushort* __restrict__ Wqb, const float* __restrict__ bq,
              const ushort* __restrict__ Wkb, const float* __restrict__ bk,
              const ushort* __restrict__ Wvb, const float* __restrict__ bv,
              ushort* __restrict__ Qb, ushort* __restrict__ Kb,
              ushort* __restrict__ VtB)
{
    __shared__ ushort As[10240], Bs[10240];
    const int z = blockIdx.z;
    const ushort* W   = (z == 0) ? Wqb : (z == 1) ? Wkb : Wvb;
    const float* bias = (z == 0) ? bq  : (z == 1) ? bk  : bv;

    f32x4 acc[4][4];
#pragma unroll
    for (int i = 0; i < 4; i++)
#pragma unroll
        for (int j = 0; j < 4; j++) acc[i][j] = (f32x4){0.f, 0.f, 0.f, 0.f};

    mfma_gemm_acc(xb, W, acc, As, Bs);

    const int t = threadIdx.x;
    const int w = t >> 6, lane = t & 63, lx = lane & 15, quad = lane >> 4;
    const int wr = w >> 1, wc = w & 1;
    const int bm = blockIdx.x, bn = blockIdx.y;

    float bvv[4];
#pragma unroll
    for (int nt = 0; nt < 4; nt++)
        bvv[nt] = bias[bn * 128 + wc * 64 + nt * 16 + lx];

    if (z < 2) {
        ushort* O = (z == 0) ? Qb : Kb;
#pragma unroll
        for (int mt = 0; mt < 4; mt++) {
            int m0 = bm * 128 + wr * 64 + mt * 16 + quad * 4;
            int bb = m0 >> 9, q = m0 & 511;
#pragma unroll
            for (int nt = 0; nt < 4; nt++) {
                int n = bn * 128 + wc * 64 + nt * 16 + lx;
                int hh = n >> 6, d = n & 63;
                size_t base = ((size_t)(bb * NH + hh) * TT + q) * HD + d;
#pragma unroll
                for (int i = 0; i < 4; i++)
                    O[base + (size_t)i * HD] = f2bf(acc[mt][nt][i] + bvv[nt]);
            }
        }
    } else {
#pragma unroll
        for (int mt = 0; mt < 4; mt++) {
            int m0 = bm * 128 + wr * 64 + mt * 16 + quad * 4;
            int bb = m0 >> 9, k = m0 & 511;
            int kt = k >> 6, kw = k & 63;
#pragma unroll
            for (int nt = 0; nt < 4; nt++) {
                int n = bn * 128 + wc * 64 + nt * 16 + lx;
                int hh = n >> 6, d = n & 63;
                uint2 pk;
                pk.x = f2bf2(acc[mt][nt][0] + bvv[nt], acc[mt][nt][1] + bvv[nt]);
                pk.y = f2bf2(acc[mt][nt][2] + bvv[nt], acc[mt][nt][3] + bvv[nt]);
                *(uint2*)&VtB[(size_t)((bb * NH + hh) * 8 + kt) * 4096 + d * 64 + kw] = pk;
            }
        }
    }
}

__global__ __launch_bounds__(256)
void proj_mfma(const ushort* __restrict__ y1, const ushort* __restrict__ Wpb,
               const float* __restrict__ bp, float* __restrict__ out)
{
    __shared__ ushort As[10240], Bs[10240];
    f32x4 acc[4][4];
#pragma unroll
    for (int i = 0; i < 4; i++)
#pragma unroll
        for (int j = 0; j < 4; j++) acc[i][j] = (f32x4){0.f, 0.f, 0.f, 0.f};

    mfma_gemm_acc(y1, Wpb, acc, As, Bs);

    const int t = threadIdx.x;
    const int w = t >> 6, lane = t & 63, lx = lane & 15, quad = lane >> 4;
    const int wr = w >> 1, wc = w & 1;
    const int bm = blockIdx.x, bn = blockIdx.y;
#pragma unroll
    for (int nt = 0; nt < 4; nt++) {
        int n = bn * 128 + wc * 64 + nt * 16 + lx;
        float bvv = bp[n];
#pragma unroll
        for (int mt = 0; mt < 4; mt++) {
            int m0 = bm * 128 + wr * 64 + mt * 16 + quad * 4;
#pragma unroll
            for (int i = 0; i < 4; i++)
                out[(size_t)(m0 + i) * CC + n] = acc[mt][nt][i] + bvv;
        }
    }
}

// ---------------------------------------------------------------------------
// adj_f_mfma v6: v5 + prefetch DISTANCE 2 via counted vmcnt (m135 semantics).
// 3-buffer rotation; iteration top waits vmcnt(3) (drain to the needed
// buffer's 3 loads; the newer 3 stay in flight) for it<6, vmcnt(0) for the
// tail. Each DMA now gets ~2 iterations (~1200 cyc) of cover instead of 1.
// Loop fully unrolled so buffer indices and waitcnt literals are static.
// Tests the "DMA latency > 1 iteration" hypothesis; everything else as R9.
// ---------------------------------------------------------------------------
__device__ __forceinline__ float gelu_s(float x) {
    float x2 = x * x;
    float u  = __builtin_fmaf(x2, 0.025f, -0.166666666666667f);
    u        = __builtin_fmaf(x2, u, 1.0f);
    float er = 0.79788456080286536f * x * u;
    return 0.5f * x * (1.0f + er);
}

__global__ __launch_bounds__(256)
void adj_f_mfma(const float* __restrict__ adj, const float* __restrict__ A1,
                const float* __restrict__ A2, const float* __restrict__ adjw_p,
                ushort* __restrict__ Fb)
{
    __shared__ float A1s[288];
    __shared__ float A2s[288];
    __shared__ __align__(16) float adjS[4][3][192];   // per-wave 3-buf, 768B each
    __shared__ __align__(8)  ushort Fs[12 * 516];     // F tile [h][k], pad 516

    const int t = threadIdx.x;
    for (int i = t; i < 288; i += 256) { A1s[i] = A1[i]; A2s[i] = A2[i]; }
    __syncthreads();

    const int w = t >> 6, lane = t & 63, lx = lane & 15, qd = lane >> 4;
    const int q = blockIdx.x, b = blockIdx.y;
    const float adjw = adjw_p[0];

    union { bf16x8 v; ushort u[8]; } b1a, b1b;
#pragma unroll
    for (int j = 0; j < 8; j++) {
        int f = qd * 8 + j;
        b1a.u[j] = (f < 12) ? f2bf(A1s[lx * 12 + f]) : (ushort)0;
        b1b.u[j] = (lx < 8 && f < 12) ? f2bf(A1s[(16 + lx) * 12 + f]) : (ushort)0;
    }
    union { bf16x4 v; ushort u[4]; } B2lo, B2hi;
#pragma unroll
    for (int j = 0; j < 4; j++) {
        int elo = qd * 4 + j;
        int ehi = 16 + qd * 4 + j;
        B2lo.u[j] = (lx < 12) ? f2bf(adjw * A2s[lx * 24 + elo]) : (ushort)0;
        B2hi.u[j] = (lx < 12 && ehi < 24) ? f2bf(adjw * A2s[lx * 24 + ehi]) : (ushort)0;
    }

    const size_t prow = ((size_t)b * TT + q) * TT;

#if __has_builtin(__builtin_amdgcn_global_load_lds)
    const char* gbase = (const char*)(adj + (prow + w * 16) * ADJF);
    // prologue: issue iterations 0 and 1 (distance-2 fill)
#pragma unroll
    for (int c = 0; c < 3; c++)
        __builtin_amdgcn_global_load_lds(
            (const __attribute__((address_space(1))) void*)(gbase + c * 256 + lane * 4),
            (__attribute__((address_space(3))) void*)&adjS[w][0][c * 64], 4, 0, 0);
#pragma unroll
    for (int c = 0; c < 3; c++)
        __builtin_amdgcn_global_load_lds(
            (const __attribute__((address_space(1))) void*)(gbase + 3072 + c * 256 + lane * 4),
            (__attribute__((address_space(3))) void*)&adjS[w][1][c * 64], 4, 0, 0);
#endif

#pragma unroll
    for (int it = 0; it < 8; it++) {
        const int k0 = it * 64 + w * 16;
        const int buf = it % 3;

#if __has_builtin(__builtin_amdgcn_global_load_lds)
        // drain to the needed buffer: 3 newer loads (it+1) stay in flight
        if (it < 6) asm volatile("s_waitcnt vmcnt(3)" ::: "memory");
        else        asm volatile("s_waitcnt vmcnt(0)" ::: "memory");
        __builtin_amdgcn_sched_barrier(0);
        if (it < 6) {
            const char* gn = gbase + (size_t)(it + 2) * 3072;   // +128 rows
            const int nb = (it + 2) % 3;
#pragma unroll
            for (int c = 0; c < 3; c++)
                __builtin_amdgcn_global_load_lds(
                    (const __attribute__((address_space(1))) void*)(gn + c * 256 + lane * 4),
                    (__attribute__((address_space(3))) void*)&adjS[w][nb][c * 64], 4, 0, 0);
        }
        const float* L = &adjS[w][buf][lx * 12];
#else
        const float* L = adj + (prow + k0 + lx) * ADJF;
#endif

        union { bf16x8 v; unsigned u[4]; } afr;
        if (qd == 0) {
            float4 u0 = *(const float4*)(L);
            float4 u1 = *(const float4*)(L + 4);
            afr.u[0] = f2bf2(u0.x, u0.y); afr.u[1] = f2bf2(u0.z, u0.w);
            afr.u[2] = f2bf2(u1.x, u1.y); afr.u[3] = f2bf2(u1.z, u1.w);
        } else if (qd == 1) {
            float4 u0 = *(const float4*)(L + 8);
            afr.u[0] = f2bf2(u0.x, u0.y); afr.u[1] = f2bf2(u0.z, u0.w);
            afr.u[2] = 0; afr.u[3] = 0;
        } else {
            afr.u[0] = 0; afr.u[1] = 0; afr.u[2] = 0; afr.u[3] = 0;
        }

        f32x4 zz = (f32x4){0.f, 0.f, 0.f, 0.f};
        f32x4 c1a = MFMA16(b1a.v, afr.v, zz);
        f32x4 c1b = MFMA16(b1b.v, afr.v, zz);

        union { bf16x4 v; unsigned u[2]; } ga, gb;
        ga.u[0] = f2bf2(gelu_s(c1a[0]), gelu_s(c1a[1]));
        ga.u[1] = f2bf2(gelu_s(c1a[2]), gelu_s(c1a[3]));
        gb.u[0] = f2bf2(gelu_s(c1b[0]), gelu_s(c1b[1]));
        gb.u[1] = f2bf2(gelu_s(c1b[2]), gelu_s(c1b[3]));

        f32x4 c2 = MFMA16K(ga.v, B2lo.v, MFMA16K(gb.v, B2hi.v, zz));

        if (lx < 12) {
            uint2 pk;
            pk.x = f2bf2(c2[0], c2[1]);
            pk.y = f2bf2(c2[2], c2[3]);
            *(uint2*)&Fs[lx * 516 + k0 + qd * 4] = pk;
        }
    }

    __syncthreads();
    // coalesced writeout: 12 rows x 1KB, 256 threads x 4B each
    ushort* outb = Fb + (size_t)b * NH * TT * TT + (size_t)q * TT;
#pragma unroll
    for (int h = 0; h < NH; h++) {
        unsigned v = *(const unsigned*)&Fs[h * 516 + t * 2];
        *(unsigned*)&outb[(size_t)h * TT * TT + t * 2] = v;
    }
}

// ---------------------------------------------------------------------------
// flash_mfma v6 (unchanged): contiguous per-head layouts + XCD swizzle.
// ---------------------------------------------------------------------------
__global__ __launch_bounds__(256)
void flash_mfma(const ushort* __restrict__ Qh, const ushort* __restrict__ Kh,
                const ushort* __restrict__ VtB, const ushort* __restrict__ Fb,
                const float* __restrict__ pad, ushort* __restrict__ y1)
{
    __shared__ ushort Ps[4][16][72];

    const int t = threadIdx.x, w = t >> 6, lane = t & 63;
    const int lx = lane & 15, quad = lane >> 4;

    const int id  = blockIdx.x + 8 * blockIdx.y + 96 * blockIdx.z;
    const int xcd = id & 7, j = id >> 3;
    const int pair = xcd * 12 + (j >> 3);
    const int qt  = j & 7;
    const int h   = pair % NH, b = pair / NH;

    const int q0 = qt * 64;
    const int bh = b * NH + h;

    const ushort* Qrow = Qh + ((size_t)bh * TT + q0 + w * 16 + lx) * HD + quad * 8;
    bf16x8 qa0 = *(const bf16x8*)Qrow;
    bf16x8 qa1 = *(const bf16x8*)(Qrow + 32);

    const float kq = 1.0f - pad[b * TT + q0 + w * 16 + lx];

    f32x4 o[4], o2[4];
#pragma unroll
    for (int i = 0; i < 4; i++) {
        o[i]  = (f32x4){0.f, 0.f, 0.f, 0.f};
        o2[i] = (f32x4){0.f, 0.f, 0.f, 0.f};
    }
    float ls = 0.f;

    const ushort* Frow  = Fb + (size_t)(bh * TT + q0 + w * 16 + lx) * TT + quad * 8;
    const float*  padk  = pad + b * TT;
    const ushort* Vbase = VtB + (size_t)bh * 8 * 4096;

    for (int ck = 0; ck < 8; ck++) {
        const int k0 = ck * 64;

        bf16x8 ka[4][2];
        float4 kp[4];
#pragma unroll
        for (int mt = 0; mt < 4; mt++) {
            const ushort* Krow = Kh + ((size_t)bh * TT + k0 + mt * 16 + lx) * HD + quad * 8;
            ka[mt][0] = *(const bf16x8*)Krow;
            ka[mt][1] = *(const bf16x8*)(Krow + 32);
            kp[mt] = *(const float4*)&padk[k0 + mt * 16 + quad * 4];
        }
        bf16x8 vb[4][2];
#pragma unroll
        for (int nt = 0; nt < 4; nt++) {
            const ushort* Vrow = Vbase + (size_t)ck * 4096 + (nt * 16 + lx) * 64 + quad * 8;
            vb[nt][0] = *(const bf16x8*)Vrow;
            vb[nt][1] = *(const bf16x8*)(Vrow + 32);
        }
        bf16x8 fa0 = *(const bf16x8*)(Frow + k0);
        bf16x8 fa1 = *(const bf16x8*)(Frow + k0 + 32);

        f32x4 st[4];
#pragma unroll
        for (int mt = 0; mt < 4; mt++) {
            f32x4 z = (f32x4){0.f, 0.f, 0.f, 0.f};
            z = MFMA16(ka[mt][0], qa0, z);
            z = MFMA16(ka[mt][1], qa1, z);
            st[mt] = z;
        }

#pragma unroll
        for (int mt = 0; mt < 4; mt++) {
            float pv[4];
#pragma unroll
            for (int i = 0; i < 4; i++) {
                float kpad = ((const float*)&kp[mt])[i];
                float p = __builtin_amdgcn_exp2f(st[mt][i] * 0.18033688011112042f);
                p = (kpad != 0.0f) ? 0.0f : p;
                p = (kq == 0.0f) ? 1.0f : p;
                pv[i] = p; ls += p;
            }
            uint2 pk;
            pk.x = f2bf2(pv[0], pv[1]);
            pk.y = f2bf2(pv[2], pv[3]);
            *(uint2*)&Ps[w][lx][mt * 16 + quad * 4] = pk;
        }
        asm volatile("s_waitcnt lgkmcnt(0)" ::: "memory");
        bf16x8 pa0 = *(const bf16x8*)&Ps[w][lx][quad * 8];
        bf16x8 pa1 = *(const bf16x8*)&Ps[w][lx][32 + quad * 8];

#pragma unroll
        for (int nt = 0; nt < 4; nt++) {
            o[nt]  = MFMA16(pa0, vb[nt][0], o[nt]);
            o[nt]  = MFMA16(pa1, vb[nt][1], o[nt]);
            o2[nt] = MFMA16(fa0, vb[nt][0], o2[nt]);
            o2[nt] = MFMA16(fa1, vb[nt][1], o2[nt]);
        }
    }
    ls += __shfl_xor(ls, 16, 64);
    ls += __shfl_xor(ls, 32, 64);
    float inv[4];
#pragma unroll
    for (int i = 0; i < 4; i++)
        inv[i] = 1.0f / __shfl(ls, quad * 4 + i, 16);
#pragma unroll
    for (int nt = 0; nt < 4; nt++)
#pragma unroll
        for (int i = 0; i < 4; i++)
            y1[(size_t)(b * TT + q0 + w * 16 + quad * 4 + i) * CC + h * HD + nt * 16 + lx] =
                f2bf(o[nt][i] * inv[i] + o2[nt][i]);
}

// ---------------------------------------------------------------------------
extern "C" void kernel_launch(void* const* d_in, const int* in_sizes, int n_in,
                              void* d_out, int out_size, void* d_ws, size_t ws_size,
                              hipStream_t stream)
{
    const float* x    = (const float*)d_in[0];
    const float* pad  = (const float*)d_in[1];
    const float* adj  = (const float*)d_in[2];
    const float* Wq   = (const float*)d_in[3];
    const float* bq   = (const float*)d_in[4];
    const float* Wk   = (const float*)d_in[5];
    const float* bk   = (const float*)d_in[6];
    const float* Wv   = (const float*)d_in[7];
    const float* bv   = (const float*)d_in[8];
    const float* Wp   = (const float*)d_in[9];
    const float* bp   = (const float*)d_in[10];
    const float* A1   = (const float*)d_in[11];
    const float* A2   = (const float*)d_in[12];
    const float* adjw = (const float*)d_in[13];

    ushort* ws  = (ushort*)d_ws;
    ushort* Fb  = ws;                     // 25,165,824 (B*H*T*T)
    ushort* Qb  = Fb + 25165824;          // 3,145,728 each
    ushort* Kb  = Qb + 3145728;
    ushort* Vt  = Kb + 3145728;
    ushort* y1  = Vt + 3145728;
    ushort* xb  = y1 + 3145728;
    ushort* Wqb = xb + 3145728;           // 589,824 each
    ushort* Wkb = Wqb + 589824;
    ushort* Wvb = Wkb + 589824;
    ushort* Wpb = Wvb + 589824;
    float*  out = (float*)d_out;

    cast5<<<dim3(1536, 5), 256, 0, stream>>>(x, Wq, Wk, Wv, Wp,
                                             xb, Wqb, Wkb, Wvb, Wpb);
    qkv_mfma<<<dim3(32, 6, 3), 256, 0, stream>>>(xb, Wqb, bq, Wkb, bk, Wvb, bv,
                                                 Qb, Kb, Vt);
    adj_f_mfma<<<dim3(512, 8), 256, 0, stream>>>(adj, A1, A2, adjw, Fb);
    flash_mfma<<<dim3(8, 12, 8), 256, 0, stream>>>(Qb, Kb, Vt, Fb, pad, y1);
    proj_mfma<<<dim3(32, 6), 256, 0, stream>>>(y1, Wpb, bp, out);
}